// Round 8
// baseline (412.375 us; speedup 1.0000x reference)
//
#include <hip/hip_runtime.h>
#include <hip/hip_fp16.h>
#include <math.h>

#define D_IN 16
#define D    64
#define H    128
#define EPSL 1e-5f

// =======================================================================
// Preprocessing (round-6 proven): hist + hierarchical scan + XCD-grouped
// fill (k_fill_x: block group g=bid&7 handles edges with (dst>>4)&7==g so
// all stores to a csr line come from one XCD's L2 -> one writeback/line).
// =======================================================================

__global__ void k_zero(int* __restrict__ p, int n)
{
    int i = blockIdx.x * blockDim.x + threadIdx.x;
    if (i < n) p[i] = 0;
}

__global__ void k_hist(const int* __restrict__ dst, int* __restrict__ cnt, int E)
{
    int i = blockIdx.x * blockDim.x + threadIdx.x;
    if (i < E) atomicAdd(&cnt[dst[i]], 1);
}

__global__ void k_scan_blk(const int* __restrict__ cnt, int* __restrict__ off,
                           int* __restrict__ bsum, int N)
{
    __shared__ int sm[256];
    int t = threadIdx.x;
    int g = blockIdx.x * 256 + t;
    int v = (g < N) ? cnt[g] : 0;
    sm[t] = v;
    __syncthreads();
    for (int d2 = 1; d2 < 256; d2 <<= 1) {
        int u = (t >= d2) ? sm[t - d2] : 0;
        __syncthreads();
        sm[t] += u;
        __syncthreads();
    }
    if (g < N) off[g + 1] = sm[t];
    if (t == 255) bsum[blockIdx.x] = sm[255];
}

__global__ void k_scan_top(int* __restrict__ bsum, int G)
{
    __shared__ int sm[1024];
    int t = threadIdx.x;
    int v = (t < G) ? bsum[t] : 0;
    sm[t] = v;
    __syncthreads();
    for (int d2 = 1; d2 < 1024; d2 <<= 1) {
        int u = (t >= d2) ? sm[t - d2] : 0;
        __syncthreads();
        sm[t] += u;
        __syncthreads();
    }
    if (t < G) bsum[t] = sm[t] - v;   // exclusive
}

__global__ void k_scan_add(int* __restrict__ off, const int* __restrict__ bsum, int N)
{
    int g = blockIdx.x * 256 + threadIdx.x;
    if (g < N) off[g + 1] += bsum[blockIdx.x];
    if (g == 0) off[0] = 0;
}

__global__ __launch_bounds__(256) void k_fill_x(const int* __restrict__ src,
                                                const int* __restrict__ dst,
                                                const int* __restrict__ off,
                                                int* __restrict__ fill,
                                                int* __restrict__ csr, int E)
{
    int g = blockIdx.x & 7;
    int j = blockIdx.x >> 3;
    int J = gridDim.x >> 3;
    for (int e = j * 256 + threadIdx.x; e < E; e += J * 256) {
        int d = dst[e];
        if (((d >> 4) & 7) == g) {
            int p = atomicAdd(&fill[d], 1);
            csr[off[d] + p] = src[e];
        }
    }
}

// =======================================================================
// GEMM-tiled MLP v3: 512 threads/block, SAME 64-node tile + 48KB LDS.
// Round 7: 782 blocks x 4 waves = 12 waves/CU -> latency-bound at
// VALUBusy 28%. v3 doubles waves/block (8) at unchanged grid/LDS ->
// 24 waves/CU. ch = tid&31 (4 hidden ch / 2 out ch per thread),
// q = tid>>5 (node quad). Per-thread FMA halves -> VGPR ~56 (<=64 keeps
// 8 waves/SIMD legal). LDS patterns: stage b32 conflict-free; phase reads
// are quarter-wave broadcasts; gT writes 2-way (free, m136); swizzle
// chunk = q ^ (row>>3), row>>3 == ch>>1 for the writer.
// m is written as FP16 (__half2): post-LN values |m|<~3, fp16 error
// ~5e-4 << tolerance; halves k_agg's gather bytes and our WRITE_SIZE.
// =======================================================================
__global__ __launch_bounds__(512) void k_mlp(const float* __restrict__ h,
                                             const float* __restrict__ wa,  // [64][128]
                                             const float* __restrict__ ba,  // [128]
                                             const float* __restrict__ wb,  // [128][64]
                                             const float* __restrict__ bb,  // [64]
                                             __half* __restrict__ m, int N)
{
    __shared__ __align__(16) float hT[D * 64];   // [k][node] 16KB
    __shared__ __align__(16) float gT[H * 64];   // [hid][node] swizzled 32KB

    const int tid  = threadIdx.x;
    const int ch   = tid & 31;          // channel group 0..31
    const int q    = tid >> 5;          // node quad 0..15
    const int base = blockIdx.x * 64;

    // stage h -> hT (transposed): 8 floats/thread, b32 writes conflict-free
    {
        int sn = tid & 63;
        int sc = tid >> 6;              // 0..7 (8-float chunk)
        int gn = min(base + sn, N - 1);
        const float4* hp = (const float4*)(h + (size_t)gn * D + sc * 8);
        float4 a = hp[0], b = hp[1];
        float* w = hT + (sc * 8) * 64 + sn;
        w[0*64]=a.x; w[1*64]=a.y; w[2*64]=a.z; w[3*64]=a.w;
        w[4*64]=b.x; w[5*64]=b.y; w[6*64]=b.z; w[7*64]=b.w;
    }
    __syncthreads();

    // phase 1: hidden channels 4ch..4ch+3 for nodes 4q..4q+3
    float acc[4][4];
#pragma unroll
    for (int i = 0; i < 4; ++i)
#pragma unroll
        for (int c = 0; c < 4; ++c) acc[i][c] = 0.f;

#pragma unroll 4
    for (int k = 0; k < D; ++k) {
        float4 w  = *(const float4*)(wa + k * H + ch * 4);
        float4 hv = *(const float4*)(hT + k * 64 + q * 4);   // broadcast b128
#define PP(i, hc) \
        acc[i][0]=fmaf(hc,w.x,acc[i][0]); acc[i][1]=fmaf(hc,w.y,acc[i][1]); \
        acc[i][2]=fmaf(hc,w.z,acc[i][2]); acc[i][3]=fmaf(hc,w.w,acc[i][3]);
        PP(0, hv.x) PP(1, hv.y) PP(2, hv.z) PP(3, hv.w)
#undef PP
    }

    // relu + write gT rows r = 4ch+c (r>>3 == ch>>1), b128 chunk-swizzled
    {
        float4 bav = *(const float4*)(ba + ch * 4);
        float bz[4] = {bav.x, bav.y, bav.z, bav.w};
        int chunk = q ^ (ch >> 1);
#pragma unroll
        for (int c = 0; c < 4; ++c) {
            int r = ch * 4 + c;
            float4 t;
            t.x = fmaxf(acc[0][c] + bz[c], 0.f);
            t.y = fmaxf(acc[1][c] + bz[c], 0.f);
            t.z = fmaxf(acc[2][c] + bz[c], 0.f);
            t.w = fmaxf(acc[3][c] + bz[c], 0.f);
            *(float4*)(gT + r * 64 + chunk * 4) = t;
        }
    }
    __syncthreads();

    // phase 2: out channels 2ch..2ch+1 over k=0..127
    float2 o0 = {0,0}, o1 = {0,0}, o2 = {0,0}, o3 = {0,0};
#pragma unroll 8
    for (int k = 0; k < H; ++k) {
        float2 w = *(const float2*)(wb + k * D + ch * 2);
        int ck = q ^ ((k >> 3) & 15);
        float4 g = *(const float4*)(gT + k * 64 + ck * 4);   // broadcast b128
        o0.x = fmaf(g.x, w.x, o0.x); o0.y = fmaf(g.x, w.y, o0.y);
        o1.x = fmaf(g.y, w.x, o1.x); o1.y = fmaf(g.y, w.y, o1.y);
        o2.x = fmaf(g.z, w.x, o2.x); o2.y = fmaf(g.z, w.y, o2.y);
        o3.x = fmaf(g.w, w.x, o3.x); o3.y = fmaf(g.w, w.y, o3.y);
    }

    // bias + SiLU + LN partials
    float2 bbv = *(const float2*)(bb + ch * 2);
    float s[4], qv[4];
#define FIN(i, ov) { \
        float tx = ov.x + bbv.x, ty = ov.y + bbv.y; \
        tx = tx / (1.f + __expf(-tx)); ty = ty / (1.f + __expf(-ty)); \
        ov.x = tx; ov.y = ty; \
        s[i] = tx + ty; qv[i] = fmaf(tx, tx, ty * ty); }
    FIN(0, o0) FIN(1, o1) FIN(2, o2) FIN(3, o3)
#undef FIN

    // reduce across the 32 in-wave channel owners (lanes 0..31 / 32..63)
#pragma unroll
    for (int d2 = 1; d2 < 32; d2 <<= 1) {
#pragma unroll
        for (int i = 0; i < 4; ++i) {
            s[i]  += __shfl_xor(s[i],  d2, 64);
            qv[i] += __shfl_xor(qv[i], d2, 64);
        }
    }

#pragma unroll
    for (int i = 0; i < 4; ++i) {
        float mu  = s[i] * (1.f / D);
        float var = qv[i] * (1.f / D) - mu * mu;
        float inv = rsqrtf(var + EPSL);
        int node = base + q * 4 + i;
        if (node < N) {
            float2 ov = (i == 0) ? o0 : (i == 1) ? o1 : (i == 2) ? o2 : o3;
            __half2 hv2 = __floats2half2_rn((ov.x - mu) * inv, (ov.y - mu) * inv);
            *(__half2*)(m + (size_t)node * D + ch * 2) = hv2;
        }
    }
}

// =======================================================================
// Initial embedding (round-7 proven v2 structure, fp32 h output).
// =======================================================================
__global__ __launch_bounds__(256) void k_init(const float* __restrict__ x,
                                              const float* __restrict__ w0,  // [16][64]
                                              const float* __restrict__ b0,
                                              const float* __restrict__ w1,  // [64][64]
                                              const float* __restrict__ b1,
                                              float* __restrict__ h, int N)
{
    __shared__ __align__(16) float xT[D_IN * 64];
    __shared__ __align__(16) float gT[D * 64];

    const int tid  = threadIdx.x;
    const int ch   = tid & 15;
    const int q    = tid >> 4;
    const int base = blockIdx.x * 64;

    {
        int sn = tid & 63;
        int sc = tid >> 6;
        int gn = min(base + sn, N - 1);
        float4 xv = *(const float4*)(x + (size_t)gn * D_IN + sc * 4);
        float* w = xT + (sc * 4) * 64 + sn;
        w[0*64] = xv.x; w[1*64] = xv.y; w[2*64] = xv.z; w[3*64] = xv.w;
    }
    __syncthreads();

    float acc[4][4];
#pragma unroll
    for (int i = 0; i < 4; ++i)
#pragma unroll
        for (int c = 0; c < 4; ++c) acc[i][c] = 0.f;

#pragma unroll
    for (int k = 0; k < D_IN; ++k) {
        float4 w = *(const float4*)(w0 + k * D + ch * 4);
        float4 xv = *(const float4*)(xT + k * 64 + q * 4);
#define PP(i, xc) \
        acc[i][0]=fmaf(xc,w.x,acc[i][0]); acc[i][1]=fmaf(xc,w.y,acc[i][1]); \
        acc[i][2]=fmaf(xc,w.z,acc[i][2]); acc[i][3]=fmaf(xc,w.w,acc[i][3]);
        PP(0, xv.x) PP(1, xv.y) PP(2, xv.z) PP(3, xv.w)
#undef PP
    }

    {
        float4 b0v = *(const float4*)(b0 + ch * 4);
        float bav[4] = {b0v.x, b0v.y, b0v.z, b0v.w};
        int chunk = q ^ (ch >> 1);      // r = 4ch+c -> r>>3 = ch>>1
#pragma unroll
        for (int c = 0; c < 4; ++c) {
            int r = ch * 4 + c;
            float4 t;
            t.x = fmaxf(acc[0][c] + bav[c], 0.f);
            t.y = fmaxf(acc[1][c] + bav[c], 0.f);
            t.z = fmaxf(acc[2][c] + bav[c], 0.f);
            t.w = fmaxf(acc[3][c] + bav[c], 0.f);
            *(float4*)(gT + r * 64 + chunk * 4) = t;
        }
    }
    __syncthreads();

    float4 o0 = {0,0,0,0}, o1 = {0,0,0,0}, o2 = {0,0,0,0}, o3 = {0,0,0,0};
#pragma unroll 8
    for (int k = 0; k < D; ++k) {
        float4 w = *(const float4*)(w1 + k * D + ch * 4);
        int chunk = q ^ ((k >> 3) & 15);
        float4 g = *(const float4*)(gT + k * 64 + chunk * 4);
        o0.x=fmaf(g.x,w.x,o0.x); o0.y=fmaf(g.x,w.y,o0.y); o0.z=fmaf(g.x,w.z,o0.z); o0.w=fmaf(g.x,w.w,o0.w);
        o1.x=fmaf(g.y,w.x,o1.x); o1.y=fmaf(g.y,w.y,o1.y); o1.z=fmaf(g.y,w.z,o1.z); o1.w=fmaf(g.y,w.w,o1.w);
        o2.x=fmaf(g.z,w.x,o2.x); o2.y=fmaf(g.z,w.y,o2.y); o2.z=fmaf(g.z,w.z,o2.z); o2.w=fmaf(g.z,w.w,o2.w);
        o3.x=fmaf(g.w,w.x,o3.x); o3.y=fmaf(g.w,w.y,o3.y); o3.z=fmaf(g.w,w.z,o3.z); o3.w=fmaf(g.w,w.w,o3.w);
    }

    float4 bbv = *(const float4*)(b1 + ch * 4);
    float s[4], qv[4];
#define FIN(i, ov) { \
        ov.x += bbv.x; ov.y += bbv.y; ov.z += bbv.z; ov.w += bbv.w; \
        ov.x = ov.x / (1.f + __expf(-ov.x)); ov.y = ov.y / (1.f + __expf(-ov.y)); \
        ov.z = ov.z / (1.f + __expf(-ov.z)); ov.w = ov.w / (1.f + __expf(-ov.w)); \
        s[i]  = (ov.x + ov.y) + (ov.z + ov.w); \
        qv[i] = fmaf(ov.x, ov.x, fmaf(ov.y, ov.y, fmaf(ov.z, ov.z, ov.w * ov.w))); }
    FIN(0, o0) FIN(1, o1) FIN(2, o2) FIN(3, o3)
#undef FIN

#pragma unroll
    for (int d2 = 1; d2 < 16; d2 <<= 1) {
#pragma unroll
        for (int i = 0; i < 4; ++i) {
            s[i]  += __shfl_xor(s[i],  d2, 64);
            qv[i] += __shfl_xor(qv[i], d2, 64);
        }
    }

#pragma unroll
    for (int i = 0; i < 4; ++i) {
        float mu  = s[i] * (1.f / D);
        float var = qv[i] * (1.f / D) - mu * mu;
        float inv = rsqrtf(var + EPSL);
        int node = base + q * 4 + i;
        if (node < N) {
            float4 ov = (i == 0) ? o0 : (i == 1) ? o1 : (i == 2) ? o2 : o3;
            float4 outv;
            outv.x = (ov.x - mu) * inv;
            outv.y = (ov.y - mu) * inv;
            outv.z = (ov.z - mu) * inv;
            outv.w = (ov.w - mu) * inv;
            *(float4*)(h + (size_t)node * D + ch * 4) = outv;
        }
    }
}

// ---------------- aggregation: h += segment_mean(m[src], dst) ------------------
// m is fp16: 8B (int2 = 4 half) per lane per edge -> half the gather bytes
__global__ __launch_bounds__(256) void k_agg(const __half* __restrict__ m,
                                             const int* __restrict__ csr,
                                             const int* __restrict__ off,
                                             float* __restrict__ h, int N)
{
    int g = threadIdx.x >> 4;
    int c = threadIdx.x & 15;
    int node = blockIdx.x * 16 + g;
    if (node >= N) return;

    int b  = off[node];
    int e2 = off[node + 1];
    float4 s0 = {0.f, 0.f, 0.f, 0.f};
    float4 s1 = {0.f, 0.f, 0.f, 0.f};
    int e = b;
    for (; e + 2 <= e2; e += 2) {
        int sn0 = csr[e];
        int sn1 = csr[e + 1];
        int2 p0 = ((const int2*)(m + (size_t)sn0 * D))[c];
        int2 p1 = ((const int2*)(m + (size_t)sn1 * D))[c];
        float2 a0 = __half22float2(*reinterpret_cast<__half2*>(&p0.x));
        float2 a1 = __half22float2(*reinterpret_cast<__half2*>(&p0.y));
        float2 b0 = __half22float2(*reinterpret_cast<__half2*>(&p1.x));
        float2 b1 = __half22float2(*reinterpret_cast<__half2*>(&p1.y));
        s0.x += a0.x; s0.y += a0.y; s0.z += a1.x; s0.w += a1.y;
        s1.x += b0.x; s1.y += b0.y; s1.z += b1.x; s1.w += b1.y;
    }
    if (e < e2) {
        int sn = csr[e];
        int2 p0 = ((const int2*)(m + (size_t)sn * D))[c];
        float2 a0 = __half22float2(*reinterpret_cast<__half2*>(&p0.x));
        float2 a1 = __half22float2(*reinterpret_cast<__half2*>(&p0.y));
        s0.x += a0.x; s0.y += a0.y; s0.z += a1.x; s0.w += a1.y;
    }
    s0.x += s1.x; s0.y += s1.y; s0.z += s1.z; s0.w += s1.w;

    float dnm = fmaxf((float)(e2 - b), 1.f);
    float inv = 1.f / dnm;

    float4* hp = (float4*)(h + (size_t)node * D);
    float4 hv = hp[c];
    hv.x = fmaf(s0.x, inv, hv.x);
    hv.y = fmaf(s0.y, inv, hv.y);
    hv.z = fmaf(s0.z, inv, hv.z);
    hv.w = fmaf(s0.w, inv, hv.w);
    hp[c] = hv;
}

extern "C" void kernel_launch(void* const* d_in, const int* in_sizes, int n_in,
                              void* d_out, int out_size, void* d_ws, size_t ws_size,
                              hipStream_t stream)
{
    const float* x  = (const float*)d_in[0];
    const int*   ei = (const int*)d_in[1];
    const float* w0 = (const float*)d_in[2];
    const float* b0 = (const float*)d_in[3];
    const float* w1 = (const float*)d_in[4];
    const float* b1 = (const float*)d_in[5];
    const float* wa = (const float*)d_in[6];
    const float* ba = (const float*)d_in[7];
    const float* wb = (const float*)d_in[8];
    const float* bb = (const float*)d_in[9];

    const int N = in_sizes[0] / D_IN;
    const int E = in_sizes[1] / 2;
    const int L = in_sizes[6] / (D * H);

    const int* src = ei;
    const int* dst = ei + E;

    // workspace layout (256B aligned chunks)
    char* ws = (char*)d_ws;
    size_t o = 0;
    auto carve = [&](size_t bytes) -> char* {
        char* p = ws + o;
        o = (o + bytes + 255) & ~(size_t)255;
        return p;
    };
    __half* m   = (__half*)carve((size_t)N * D * sizeof(__half));
    int*   csr  = (int*)  carve((size_t)E * sizeof(int));
    int*   cnt  = (int*)  carve((size_t)N * sizeof(int));
    int*   fill = (int*)  carve((size_t)N * sizeof(int));
    int*   offp = (int*)  carve((size_t)(N + 1) * sizeof(int));
    int*   bsum = (int*)  carve((size_t)1024 * sizeof(int));

    float* h = (float*)d_out;

    const int nb = (N + 63) / 64;
    const int G1 = (N + 255) / 256;

    k_zero<<<(N + 255) / 256, 256, 0, stream>>>(cnt, N);
    k_zero<<<(N + 255) / 256, 256, 0, stream>>>(fill, N);
    k_hist<<<(E + 255) / 256, 256, 0, stream>>>(dst, cnt, E);
    k_scan_blk<<<G1, 256, 0, stream>>>(cnt, offp, bsum, N);
    k_scan_top<<<1, 1024, 0, stream>>>(bsum, G1);
    k_scan_add<<<G1, 256, 0, stream>>>(offp, bsum, N);
    k_fill_x<<<2048, 256, 0, stream>>>(src, dst, offp, fill, csr, E);

    k_init<<<nb, 256, 0, stream>>>(x, w0, b0, w1, b1, h, N);

    for (int l = 0; l < L; ++l) {
        k_mlp<<<nb, 512, 0, stream>>>(h, wa + (size_t)l * D * H,
                                      ba + (size_t)l * H,
                                      wb + (size_t)l * H * D,
                                      bb + (size_t)l * D, m, N);
        k_agg<<<(N + 15) / 16, 256, 0, stream>>>(m, csr, offp, h, N);
    }
}

// Round 9
// 349.082 us; speedup vs baseline: 1.1813x; 1.1813x over previous
//
#include <hip/hip_runtime.h>
#include <hip/hip_fp16.h>
#include <math.h>

#define D_IN 16
#define D    64
#define H    128
#define EPSL 1e-5f

// =======================================================================
// Preprocessing (round-6 proven): hist + hierarchical scan + XCD-grouped
// fill (k_fill_x: block group g=bid&7 handles edges with (dst>>4)&7==g so
// all stores to a csr line come from one XCD's L2 -> one writeback/line).
// =======================================================================

__global__ void k_zero(int* __restrict__ p, int n)
{
    int i = blockIdx.x * blockDim.x + threadIdx.x;
    if (i < n) p[i] = 0;
}

__global__ void k_hist(const int* __restrict__ dst, int* __restrict__ cnt, int E)
{
    int i = blockIdx.x * blockDim.x + threadIdx.x;
    if (i < E) atomicAdd(&cnt[dst[i]], 1);
}

__global__ void k_scan_blk(const int* __restrict__ cnt, int* __restrict__ off,
                           int* __restrict__ bsum, int N)
{
    __shared__ int sm[256];
    int t = threadIdx.x;
    int g = blockIdx.x * 256 + t;
    int v = (g < N) ? cnt[g] : 0;
    sm[t] = v;
    __syncthreads();
    for (int d2 = 1; d2 < 256; d2 <<= 1) {
        int u = (t >= d2) ? sm[t - d2] : 0;
        __syncthreads();
        sm[t] += u;
        __syncthreads();
    }
    if (g < N) off[g + 1] = sm[t];
    if (t == 255) bsum[blockIdx.x] = sm[255];
}

__global__ void k_scan_top(int* __restrict__ bsum, int G)
{
    __shared__ int sm[1024];
    int t = threadIdx.x;
    int v = (t < G) ? bsum[t] : 0;
    sm[t] = v;
    __syncthreads();
    for (int d2 = 1; d2 < 1024; d2 <<= 1) {
        int u = (t >= d2) ? sm[t - d2] : 0;
        __syncthreads();
        sm[t] += u;
        __syncthreads();
    }
    if (t < G) bsum[t] = sm[t] - v;   // exclusive
}

__global__ void k_scan_add(int* __restrict__ off, const int* __restrict__ bsum, int N)
{
    int g = blockIdx.x * 256 + threadIdx.x;
    if (g < N) off[g + 1] += bsum[blockIdx.x];
    if (g == 0) off[0] = 0;
}

__global__ __launch_bounds__(256) void k_fill_x(const int* __restrict__ src,
                                                const int* __restrict__ dst,
                                                const int* __restrict__ off,
                                                int* __restrict__ fill,
                                                int* __restrict__ csr, int E)
{
    int g = blockIdx.x & 7;
    int j = blockIdx.x >> 3;
    int J = gridDim.x >> 3;
    for (int e = j * 256 + threadIdx.x; e < E; e += J * 256) {
        int d = dst[e];
        if (((d >> 4) & 7) == g) {
            int p = atomicAdd(&fill[d], 1);
            csr[off[d] + p] = src[e];
        }
    }
}

// =======================================================================
// GEMM-tiled MLP (round-7 proven structure, EXACT: 256 thr, 64-node tile,
// ch=tid&15, q=tid>>4, full 4-bit write swizzle chunk=q^ch -> 0 bank
// conflicts, 47us). Round-8's 512-thread remap is REVERTED: halving
// per-thread work doubled the block's ds_read/VMEM instruction count on
// the shared pipes (and its 3-bit swizzle caused 200K conflicts) -> 59us.
// Only change vs round 7: epilogue packs m as fp16 (2x __half2, 8B store)
// -> halves m write traffic + k_agg gather bytes (round-8 proven).
// =======================================================================
__global__ __launch_bounds__(256) void k_mlp(const float* __restrict__ h,
                                             const float* __restrict__ wa,  // [64][128]
                                             const float* __restrict__ ba,  // [128]
                                             const float* __restrict__ wb,  // [128][64]
                                             const float* __restrict__ bb,  // [64]
                                             __half* __restrict__ m, int N)
{
    __shared__ __align__(16) float hT[D * 64];   // [k][node] 16KB
    __shared__ __align__(16) float gT[H * 64];   // [hid][node] swizzled 32KB

    const int tid  = threadIdx.x;
    const int ch   = tid & 15;
    const int q    = tid >> 4;          // node quad 0..15
    const int base = blockIdx.x * 64;

    // stage h -> hT (transposed). b32 writes, lanes consecutive: 2-way, free.
    {
        int sn = tid & 63;
        int sc = tid >> 6;
        int gn = min(base + sn, N - 1);
        const float4* hp = (const float4*)(h + (size_t)gn * D + sc * 16);
        float4 a = hp[0], b = hp[1], c4 = hp[2], d4 = hp[3];
        float* w = hT + (sc * 16) * 64 + sn;
        w[0*64]=a.x;  w[1*64]=a.y;  w[2*64]=a.z;  w[3*64]=a.w;
        w[4*64]=b.x;  w[5*64]=b.y;  w[6*64]=b.z;  w[7*64]=b.w;
        w[8*64]=c4.x; w[9*64]=c4.y; w[10*64]=c4.z; w[11*64]=c4.w;
        w[12*64]=d4.x; w[13*64]=d4.y; w[14*64]=d4.z; w[15*64]=d4.w;
    }
    __syncthreads();

    // phase 1: acc[node i][hid ch c] for hidden channels 8ch..8ch+7
    float acc[4][8];
#pragma unroll
    for (int i = 0; i < 4; ++i)
#pragma unroll
        for (int c = 0; c < 8; ++c) acc[i][c] = 0.f;

#pragma unroll 4
    for (int k = 0; k < D; ++k) {
        float4 wA = *(const float4*)(wa + k * H + ch * 8);
        float4 wB = *(const float4*)(wa + k * H + ch * 8 + 4);
        float4 hv = *(const float4*)(hT + k * 64 + q * 4);   // 1 b128, broadcast
#define PP(i, hc) \
        acc[i][0]=fmaf(hc,wA.x,acc[i][0]); acc[i][1]=fmaf(hc,wA.y,acc[i][1]); \
        acc[i][2]=fmaf(hc,wA.z,acc[i][2]); acc[i][3]=fmaf(hc,wA.w,acc[i][3]); \
        acc[i][4]=fmaf(hc,wB.x,acc[i][4]); acc[i][5]=fmaf(hc,wB.y,acc[i][5]); \
        acc[i][6]=fmaf(hc,wB.z,acc[i][6]); acc[i][7]=fmaf(hc,wB.w,acc[i][7]);
        PP(0, hv.x) PP(1, hv.y) PP(2, hv.z) PP(3, hv.w)
#undef PP
    }

    // relu + write hid: rows r=8ch+c, chunk-swizzled b128 (conflict-free)
    {
        float4 b0v = *(const float4*)(ba + ch * 8);
        float4 b1v = *(const float4*)(ba + ch * 8 + 4);
        float bav[8] = {b0v.x, b0v.y, b0v.z, b0v.w, b1v.x, b1v.y, b1v.z, b1v.w};
        int chunk = q ^ ch;             // = q ^ (r>>3), r = 8ch+c
#pragma unroll
        for (int c = 0; c < 8; ++c) {
            int r = ch * 8 + c;
            float4 t;
            t.x = fmaxf(acc[0][c] + bav[c], 0.f);
            t.y = fmaxf(acc[1][c] + bav[c], 0.f);
            t.z = fmaxf(acc[2][c] + bav[c], 0.f);
            t.w = fmaxf(acc[3][c] + bav[c], 0.f);
            *(float4*)(gT + r * 64 + chunk * 4) = t;
        }
    }
    __syncthreads();

    // phase 2: o[node i] over out channels 4ch..4ch+3
    float4 o0 = {0,0,0,0}, o1 = {0,0,0,0}, o2 = {0,0,0,0}, o3 = {0,0,0,0};
#pragma unroll 8
    for (int k = 0; k < H; ++k) {
        float4 w = *(const float4*)(wb + k * D + ch * 4);
        int chunk = q ^ ((k >> 3) & 15);
        float4 g = *(const float4*)(gT + k * 64 + chunk * 4);  // 1 b128
        o0.x=fmaf(g.x,w.x,o0.x); o0.y=fmaf(g.x,w.y,o0.y); o0.z=fmaf(g.x,w.z,o0.z); o0.w=fmaf(g.x,w.w,o0.w);
        o1.x=fmaf(g.y,w.x,o1.x); o1.y=fmaf(g.y,w.y,o1.y); o1.z=fmaf(g.y,w.z,o1.z); o1.w=fmaf(g.y,w.w,o1.w);
        o2.x=fmaf(g.z,w.x,o2.x); o2.y=fmaf(g.z,w.y,o2.y); o2.z=fmaf(g.z,w.z,o2.z); o2.w=fmaf(g.z,w.w,o2.w);
        o3.x=fmaf(g.w,w.x,o3.x); o3.y=fmaf(g.w,w.y,o3.y); o3.z=fmaf(g.w,w.z,o3.z); o3.w=fmaf(g.w,w.w,o3.w);
    }

    // bias + SiLU + LN (reduce across the 16 in-wave channel owners)
    float4 bbv = *(const float4*)(bb + ch * 4);
    float s[4], qv[4];
#define FIN(i, ov) { \
        ov.x += bbv.x; ov.y += bbv.y; ov.z += bbv.z; ov.w += bbv.w; \
        ov.x = ov.x / (1.f + __expf(-ov.x)); ov.y = ov.y / (1.f + __expf(-ov.y)); \
        ov.z = ov.z / (1.f + __expf(-ov.z)); ov.w = ov.w / (1.f + __expf(-ov.w)); \
        s[i]  = (ov.x + ov.y) + (ov.z + ov.w); \
        qv[i] = fmaf(ov.x, ov.x, fmaf(ov.y, ov.y, fmaf(ov.z, ov.z, ov.w * ov.w))); }
    FIN(0, o0) FIN(1, o1) FIN(2, o2) FIN(3, o3)
#undef FIN

#pragma unroll
    for (int d2 = 1; d2 < 16; d2 <<= 1) {
#pragma unroll
        for (int i = 0; i < 4; ++i) {
            s[i]  += __shfl_xor(s[i],  d2, 64);
            qv[i] += __shfl_xor(qv[i], d2, 64);
        }
    }

#pragma unroll
    for (int i = 0; i < 4; ++i) {
        float mu  = s[i] * (1.f / D);
        float var = qv[i] * (1.f / D) - mu * mu;
        float inv = rsqrtf(var + EPSL);
        int node = base + q * 4 + i;
        if (node < N) {
            float4 ov = (i == 0) ? o0 : (i == 1) ? o1 : (i == 2) ? o2 : o3;
            __half2 lo = __floats2half2_rn((ov.x - mu) * inv, (ov.y - mu) * inv);
            __half2 hi = __floats2half2_rn((ov.z - mu) * inv, (ov.w - mu) * inv);
            uint2 pk;
            pk.x = *reinterpret_cast<unsigned int*>(&lo);
            pk.y = *reinterpret_cast<unsigned int*>(&hi);
            *(uint2*)(m + (size_t)node * D + ch * 4) = pk;   // 8B store
        }
    }
}

// =======================================================================
// Initial embedding (round-7 proven, unchanged; fp32 h output).
// =======================================================================
__global__ __launch_bounds__(256) void k_init(const float* __restrict__ x,
                                              const float* __restrict__ w0,  // [16][64]
                                              const float* __restrict__ b0,
                                              const float* __restrict__ w1,  // [64][64]
                                              const float* __restrict__ b1,
                                              float* __restrict__ h, int N)
{
    __shared__ __align__(16) float xT[D_IN * 64];
    __shared__ __align__(16) float gT[D * 64];

    const int tid  = threadIdx.x;
    const int ch   = tid & 15;
    const int q    = tid >> 4;
    const int base = blockIdx.x * 64;

    {
        int sn = tid & 63;
        int sc = tid >> 6;
        int gn = min(base + sn, N - 1);
        float4 xv = *(const float4*)(x + (size_t)gn * D_IN + sc * 4);
        float* w = xT + (sc * 4) * 64 + sn;
        w[0*64] = xv.x; w[1*64] = xv.y; w[2*64] = xv.z; w[3*64] = xv.w;
    }
    __syncthreads();

    float acc[4][4];
#pragma unroll
    for (int i = 0; i < 4; ++i)
#pragma unroll
        for (int c = 0; c < 4; ++c) acc[i][c] = 0.f;

#pragma unroll
    for (int k = 0; k < D_IN; ++k) {
        float4 w = *(const float4*)(w0 + k * D + ch * 4);
        float4 xv = *(const float4*)(xT + k * 64 + q * 4);
#define PP(i, xc) \
        acc[i][0]=fmaf(xc,w.x,acc[i][0]); acc[i][1]=fmaf(xc,w.y,acc[i][1]); \
        acc[i][2]=fmaf(xc,w.z,acc[i][2]); acc[i][3]=fmaf(xc,w.w,acc[i][3]);
        PP(0, xv.x) PP(1, xv.y) PP(2, xv.z) PP(3, xv.w)
#undef PP
    }

    {
        float4 b0v = *(const float4*)(b0 + ch * 4);
        float bav[4] = {b0v.x, b0v.y, b0v.z, b0v.w};
        int chunk = q ^ (ch >> 1);      // r = 4ch+c -> r>>3 = ch>>1
#pragma unroll
        for (int c = 0; c < 4; ++c) {
            int r = ch * 4 + c;
            float4 t;
            t.x = fmaxf(acc[0][c] + bav[c], 0.f);
            t.y = fmaxf(acc[1][c] + bav[c], 0.f);
            t.z = fmaxf(acc[2][c] + bav[c], 0.f);
            t.w = fmaxf(acc[3][c] + bav[c], 0.f);
            *(float4*)(gT + r * 64 + chunk * 4) = t;
        }
    }
    __syncthreads();

    float4 o0 = {0,0,0,0}, o1 = {0,0,0,0}, o2 = {0,0,0,0}, o3 = {0,0,0,0};
#pragma unroll 8
    for (int k = 0; k < D; ++k) {
        float4 w = *(const float4*)(w1 + k * D + ch * 4);
        int chunk = q ^ ((k >> 3) & 15);
        float4 g = *(const float4*)(gT + k * 64 + chunk * 4);
        o0.x=fmaf(g.x,w.x,o0.x); o0.y=fmaf(g.x,w.y,o0.y); o0.z=fmaf(g.x,w.z,o0.z); o0.w=fmaf(g.x,w.w,o0.w);
        o1.x=fmaf(g.y,w.x,o1.x); o1.y=fmaf(g.y,w.y,o1.y); o1.z=fmaf(g.y,w.z,o1.z); o1.w=fmaf(g.y,w.w,o1.w);
        o2.x=fmaf(g.z,w.x,o2.x); o2.y=fmaf(g.z,w.y,o2.y); o2.z=fmaf(g.z,w.z,o2.z); o2.w=fmaf(g.z,w.w,o2.w);
        o3.x=fmaf(g.w,w.x,o3.x); o3.y=fmaf(g.w,w.y,o3.y); o3.z=fmaf(g.w,w.z,o3.z); o3.w=fmaf(g.w,w.w,o3.w);
    }

    float4 bbv = *(const float4*)(b1 + ch * 4);
    float s[4], qv[4];
#define FIN(i, ov) { \
        ov.x += bbv.x; ov.y += bbv.y; ov.z += bbv.z; ov.w += bbv.w; \
        ov.x = ov.x / (1.f + __expf(-ov.x)); ov.y = ov.y / (1.f + __expf(-ov.y)); \
        ov.z = ov.z / (1.f + __expf(-ov.z)); ov.w = ov.w / (1.f + __expf(-ov.w)); \
        s[i]  = (ov.x + ov.y) + (ov.z + ov.w); \
        qv[i] = fmaf(ov.x, ov.x, fmaf(ov.y, ov.y, fmaf(ov.z, ov.z, ov.w * ov.w))); }
    FIN(0, o0) FIN(1, o1) FIN(2, o2) FIN(3, o3)
#undef FIN

#pragma unroll
    for (int d2 = 1; d2 < 16; d2 <<= 1) {
#pragma unroll
        for (int i = 0; i < 4; ++i) {
            s[i]  += __shfl_xor(s[i],  d2, 64);
            qv[i] += __shfl_xor(qv[i], d2, 64);
        }
    }

#pragma unroll
    for (int i = 0; i < 4; ++i) {
        float mu  = s[i] * (1.f / D);
        float var = qv[i] * (1.f / D) - mu * mu;
        float inv = rsqrtf(var + EPSL);
        int node = base + q * 4 + i;
        if (node < N) {
            float4 ov = (i == 0) ? o0 : (i == 1) ? o1 : (i == 2) ? o2 : o3;
            float4 outv;
            outv.x = (ov.x - mu) * inv;
            outv.y = (ov.y - mu) * inv;
            outv.z = (ov.z - mu) * inv;
            outv.w = (ov.w - mu) * inv;
            *(float4*)(h + (size_t)node * D + ch * 4) = outv;
        }
    }
}

// ---------------- aggregation: h += segment_mean(m[src], dst) ------------------
// m fp16 (8B per lane per edge); unroll 4 -> 4 gather lines in flight
__global__ __launch_bounds__(256) void k_agg(const __half* __restrict__ m,
                                             const int* __restrict__ csr,
                                             const int* __restrict__ off,
                                             float* __restrict__ h, int N)
{
    int g = threadIdx.x >> 4;
    int c = threadIdx.x & 15;
    int node = blockIdx.x * 16 + g;
    if (node >= N) return;

    int b  = off[node];
    int e2 = off[node + 1];
    float4 s0 = {0.f, 0.f, 0.f, 0.f};
    float4 s1 = {0.f, 0.f, 0.f, 0.f};
    int e = b;
#define GATH(sacc, pv) { \
        float2 u0 = __half22float2(*reinterpret_cast<__half2*>(&pv.x)); \
        float2 u1 = __half22float2(*reinterpret_cast<__half2*>(&pv.y)); \
        sacc.x += u0.x; sacc.y += u0.y; sacc.z += u1.x; sacc.w += u1.y; }
    for (; e + 4 <= e2; e += 4) {
        int sn0 = csr[e], sn1 = csr[e + 1], sn2 = csr[e + 2], sn3 = csr[e + 3];
        int2 p0 = ((const int2*)(m + (size_t)sn0 * D))[c];
        int2 p1 = ((const int2*)(m + (size_t)sn1 * D))[c];
        int2 p2 = ((const int2*)(m + (size_t)sn2 * D))[c];
        int2 p3 = ((const int2*)(m + (size_t)sn3 * D))[c];
        GATH(s0, p0) GATH(s1, p1) GATH(s0, p2) GATH(s1, p3)
    }
    for (; e < e2; ++e) {
        int sn = csr[e];
        int2 p = ((const int2*)(m + (size_t)sn * D))[c];
        GATH(s0, p)
    }
#undef GATH
    s0.x += s1.x; s0.y += s1.y; s0.z += s1.z; s0.w += s1.w;

    float dnm = fmaxf((float)(e2 - b), 1.f);
    float inv = 1.f / dnm;

    float4* hp = (float4*)(h + (size_t)node * D);
    float4 hv = hp[c];
    hv.x = fmaf(s0.x, inv, hv.x);
    hv.y = fmaf(s0.y, inv, hv.y);
    hv.z = fmaf(s0.z, inv, hv.z);
    hv.w = fmaf(s0.w, inv, hv.w);
    hp[c] = hv;
}

extern "C" void kernel_launch(void* const* d_in, const int* in_sizes, int n_in,
                              void* d_out, int out_size, void* d_ws, size_t ws_size,
                              hipStream_t stream)
{
    const float* x  = (const float*)d_in[0];
    const int*   ei = (const int*)d_in[1];
    const float* w0 = (const float*)d_in[2];
    const float* b0 = (const float*)d_in[3];
    const float* w1 = (const float*)d_in[4];
    const float* b1 = (const float*)d_in[5];
    const float* wa = (const float*)d_in[6];
    const float* ba = (const float*)d_in[7];
    const float* wb = (const float*)d_in[8];
    const float* bb = (const float*)d_in[9];

    const int N = in_sizes[0] / D_IN;
    const int E = in_sizes[1] / 2;
    const int L = in_sizes[6] / (D * H);

    const int* src = ei;
    const int* dst = ei + E;

    // workspace layout (256B aligned chunks)
    char* ws = (char*)d_ws;
    size_t o = 0;
    auto carve = [&](size_t bytes) -> char* {
        char* p = ws + o;
        o = (o + bytes + 255) & ~(size_t)255;
        return p;
    };
    __half* m   = (__half*)carve((size_t)N * D * sizeof(__half));
    int*   csr  = (int*)  carve((size_t)E * sizeof(int));
    int*   cnt  = (int*)  carve((size_t)N * sizeof(int));
    int*   fill = (int*)  carve((size_t)N * sizeof(int));
    int*   offp = (int*)  carve((size_t)(N + 1) * sizeof(int));
    int*   bsum = (int*)  carve((size_t)1024 * sizeof(int));

    float* h = (float*)d_out;

    const int nb = (N + 63) / 64;
    const int G1 = (N + 255) / 256;

    k_zero<<<(N + 255) / 256, 256, 0, stream>>>(cnt, N);
    k_zero<<<(N + 255) / 256, 256, 0, stream>>>(fill, N);
    k_hist<<<(E + 255) / 256, 256, 0, stream>>>(dst, cnt, E);
    k_scan_blk<<<G1, 256, 0, stream>>>(cnt, offp, bsum, N);
    k_scan_top<<<1, 1024, 0, stream>>>(bsum, G1);
    k_scan_add<<<G1, 256, 0, stream>>>(offp, bsum, N);
    k_fill_x<<<2048, 256, 0, stream>>>(src, dst, offp, fill, csr, E);

    k_init<<<nb, 256, 0, stream>>>(x, w0, b0, w1, b1, h, N);

    for (int l = 0; l < L; ++l) {
        k_mlp<<<nb, 256, 0, stream>>>(h, wa + (size_t)l * D * H,
                                      ba + (size_t)l * H,
                                      wb + (size_t)l * H * D,
                                      bb + (size_t)l * D, m, N);
        k_agg<<<(N + 15) / 16, 256, 0, stream>>>(m, csr, offp, h, N);
    }
}

// Round 10
// 304.424 us; speedup vs baseline: 1.3546x; 1.1467x over previous
//
#include <hip/hip_runtime.h>
#include <hip/hip_fp16.h>
#include <math.h>

#define D_IN 16
#define D    64
#define H    128
#define EPSL 1e-5f

typedef _Float16 h2v __attribute__((ext_vector_type(2)));

// dot2: d = a.x*b.x + a.y*b.y + c, fp16 inputs, fp32 accumulate
__device__ __forceinline__ float dot2f(unsigned int a, unsigned int b, float c)
{
#if __has_builtin(__builtin_amdgcn_fdot2)
    return __builtin_amdgcn_fdot2(__builtin_bit_cast(h2v, a),
                                  __builtin_bit_cast(h2v, b), c, false);
#else
    __half2 ha = *reinterpret_cast<__half2*>(&a);
    __half2 hb = *reinterpret_cast<__half2*>(&b);
    float2 fa = __half22float2(ha), fb = __half22float2(hb);
    return fmaf(fa.x, fb.x, fmaf(fa.y, fb.y, c));
#endif
}

__device__ __forceinline__ unsigned int packh2(float x, float y)
{
    __half2 p = __floats2half2_rn(x, y);
    return *reinterpret_cast<unsigned int*>(&p);
}

// =======================================================================
// Preprocessing (round-6 proven): hist + hierarchical scan + XCD-grouped
// fill. Unchanged.
// =======================================================================

__global__ void k_zero(int* __restrict__ p, int n)
{
    int i = blockIdx.x * blockDim.x + threadIdx.x;
    if (i < n) p[i] = 0;
}

__global__ void k_hist(const int* __restrict__ dst, int* __restrict__ cnt, int E)
{
    int i = blockIdx.x * blockDim.x + threadIdx.x;
    if (i < E) atomicAdd(&cnt[dst[i]], 1);
}

__global__ void k_scan_blk(const int* __restrict__ cnt, int* __restrict__ off,
                           int* __restrict__ bsum, int N)
{
    __shared__ int sm[256];
    int t = threadIdx.x;
    int g = blockIdx.x * 256 + t;
    int v = (g < N) ? cnt[g] : 0;
    sm[t] = v;
    __syncthreads();
    for (int d2 = 1; d2 < 256; d2 <<= 1) {
        int u = (t >= d2) ? sm[t - d2] : 0;
        __syncthreads();
        sm[t] += u;
        __syncthreads();
    }
    if (g < N) off[g + 1] = sm[t];
    if (t == 255) bsum[blockIdx.x] = sm[255];
}

__global__ void k_scan_top(int* __restrict__ bsum, int G)
{
    __shared__ int sm[1024];
    int t = threadIdx.x;
    int v = (t < G) ? bsum[t] : 0;
    sm[t] = v;
    __syncthreads();
    for (int d2 = 1; d2 < 1024; d2 <<= 1) {
        int u = (t >= d2) ? sm[t - d2] : 0;
        __syncthreads();
        sm[t] += u;
        __syncthreads();
    }
    if (t < G) bsum[t] = sm[t] - v;   // exclusive
}

__global__ void k_scan_add(int* __restrict__ off, const int* __restrict__ bsum, int N)
{
    int g = blockIdx.x * 256 + threadIdx.x;
    if (g < N) off[g + 1] += bsum[blockIdx.x];
    if (g == 0) off[0] = 0;
}

__global__ __launch_bounds__(256) void k_fill_x(const int* __restrict__ src,
                                                const int* __restrict__ dst,
                                                const int* __restrict__ off,
                                                int* __restrict__ fill,
                                                int* __restrict__ csr, int E)
{
    int g = blockIdx.x & 7;
    int j = blockIdx.x >> 3;
    int J = gridDim.x >> 3;
    for (int e = j * 256 + threadIdx.x; e < E; e += J * 256) {
        int d = dst[e];
        if (((d >> 4) & 7) == g) {
            int p = atomicAdd(&fill[d], 1);
            csr[off[d] + p] = src[e];
        }
    }
}

// =======================================================================
// Weight prep: pack wa/wb into k-paired fp16.
// wap[l][k2][c] = (wa[l][2k2][c], wa[l][2k2+1][c])   k2 in [0,32), c in [0,128)
// wbp[l][k2][j] = (wb[l][2k2][j], wb[l][2k2+1][j])   k2 in [0,64), j in [0,64)
// Per-phase weight set becomes 16KB -> fully L1-resident (the round-9
// latency culprit: fp32 wa/wb at 32KB each thrashed the 32KB L1).
// =======================================================================
__global__ void k_prep_w(const float* __restrict__ wa, const float* __restrict__ wb,
                         unsigned int* __restrict__ wap, unsigned int* __restrict__ wbp,
                         int L)
{
    int idx = blockIdx.x * blockDim.x + threadIdx.x;
    if (idx >= L * 8192) return;
    int l = idx >> 13;
    int r = idx & 8191;
    if (r < 4096) {
        int k2 = r >> 7, c = r & 127;
        const float* base = wa + (size_t)l * D * H;
        wap[(size_t)l * 4096 + r] = packh2(base[(2 * k2) * H + c],
                                           base[(2 * k2 + 1) * H + c]);
    } else {
        r -= 4096;
        int k2 = r >> 6, j = r & 63;
        const float* base = wb + (size_t)l * H * D;
        wbp[(size_t)l * 4096 + r] = packh2(base[(2 * k2) * D + j],
                                           base[(2 * k2 + 1) * D + j]);
    }
}

// =======================================================================
// GEMM-tiled MLP v4: round-7/9 tile geometry (256 thr, 64-node tile,
// ch=tid&15, q=tid>>4, quad-XOR swizzle) with fp16-PAIR operands and
// v_dot2_f32_f16 inner loops. Per thread vs round 9: dot-ops 4096->2048,
// ds_reads 192->96, VMEM 256->128; LDS 49KB->24KB; per-phase weights
// 16KB (L1-resident). Accumulation stays fp32; epilogue (LN shfl + fp16
// m store) unchanged.
//   hT2[k2][node] : pair (h[node][2k2], h[node][2k2+1])          8KB
//   gT2[k2][node] : pair (relu-hid[2k2][node], [2k2+1][node])   16KB
// gT2 write: thread (ch,q) owns pair-rows r2=4ch+cc, writes node quad q
// at chunk = q ^ (r2&15); reader uses chunk = q ^ (k2&15). Same bijective
// swizzle as round 7 (verified: writer chunk&7 uniform 8 lanes/bank-quad).
// =======================================================================
__global__ __launch_bounds__(256) void k_mlp(const float* __restrict__ h,
                                             const unsigned int* __restrict__ wap, // [32][128] pairs
                                             const float* __restrict__ ba,         // [128]
                                             const unsigned int* __restrict__ wbp, // [64][64] pairs
                                             const float* __restrict__ bb,         // [64]
                                             __half* __restrict__ m, int N)
{
    __shared__ __align__(16) unsigned int hT2[32 * 64];  // 8KB
    __shared__ __align__(16) unsigned int gT2[64 * 64];  // 16KB

    const int tid  = threadIdx.x;
    const int ch   = tid & 15;
    const int q    = tid >> 4;          // node quad 0..15
    const int base = blockIdx.x * 64;

    // stage h -> hT2 (fp16 pairs, transposed). b32 writes, lanes consecutive.
    {
        int sn = tid & 63;
        int sc = tid >> 6;              // k-chunk 16 floats -> 8 pair rows
        int gn = min(base + sn, N - 1);
        const float4* hp = (const float4*)(h + (size_t)gn * D + sc * 16);
        float4 A = hp[0], B = hp[1], C = hp[2], Dv = hp[3];
        unsigned int* w = hT2 + (sc * 8) * 64 + sn;
        w[0 * 64] = packh2(A.x, A.y);  w[1 * 64] = packh2(A.z, A.w);
        w[2 * 64] = packh2(B.x, B.y);  w[3 * 64] = packh2(B.z, B.w);
        w[4 * 64] = packh2(C.x, C.y);  w[5 * 64] = packh2(C.z, C.w);
        w[6 * 64] = packh2(Dv.x, Dv.y); w[7 * 64] = packh2(Dv.z, Dv.w);
    }
    __syncthreads();

    // phase 1: acc[node i][hid c] for hidden channels 8ch..8ch+7, k2=0..31
    float acc[4][8];
#pragma unroll
    for (int i = 0; i < 4; ++i)
#pragma unroll
        for (int c = 0; c < 8; ++c) acc[i][c] = 0.f;

#pragma unroll 4
    for (int k2 = 0; k2 < 32; ++k2) {
        const unsigned int* wr = wap + k2 * 128 + ch * 8;
        uint4 w0 = *(const uint4*)(wr);
        uint4 w1 = *(const uint4*)(wr + 4);
        uint4 hh = *(const uint4*)(hT2 + k2 * 64 + q * 4);   // 4 nodes' pairs
#define P1(i, hv) \
        acc[i][0]=dot2f(hv,w0.x,acc[i][0]); acc[i][1]=dot2f(hv,w0.y,acc[i][1]); \
        acc[i][2]=dot2f(hv,w0.z,acc[i][2]); acc[i][3]=dot2f(hv,w0.w,acc[i][3]); \
        acc[i][4]=dot2f(hv,w1.x,acc[i][4]); acc[i][5]=dot2f(hv,w1.y,acc[i][5]); \
        acc[i][6]=dot2f(hv,w1.z,acc[i][6]); acc[i][7]=dot2f(hv,w1.w,acc[i][7]);
        P1(0, hh.x) P1(1, hh.y) P1(2, hh.z) P1(3, hh.w)
#undef P1
    }

    // bias + relu + pack to gT2 pair-rows r2 = 4ch+cc, chunk-swizzled b128
    {
        float4 b0v = *(const float4*)(ba + ch * 8);
        float4 b1v = *(const float4*)(ba + ch * 8 + 4);
        float bav[8] = {b0v.x, b0v.y, b0v.z, b0v.w, b1v.x, b1v.y, b1v.z, b1v.w};
#pragma unroll
        for (int cc = 0; cc < 4; ++cc) {
            int c0 = 2 * cc, c1 = 2 * cc + 1;
            int r2 = ch * 4 + cc;
            int chunk = q ^ (r2 & 15);
            uint4 t;
            t.x = packh2(fmaxf(acc[0][c0] + bav[c0], 0.f), fmaxf(acc[0][c1] + bav[c1], 0.f));
            t.y = packh2(fmaxf(acc[1][c0] + bav[c0], 0.f), fmaxf(acc[1][c1] + bav[c1], 0.f));
            t.z = packh2(fmaxf(acc[2][c0] + bav[c0], 0.f), fmaxf(acc[2][c1] + bav[c1], 0.f));
            t.w = packh2(fmaxf(acc[3][c0] + bav[c0], 0.f), fmaxf(acc[3][c1] + bav[c1], 0.f));
            *(uint4*)(gT2 + r2 * 64 + chunk * 4) = t;
        }
    }
    __syncthreads();

    // phase 2: o[node i][out j] for out channels 4ch..4ch+3, k2=0..63
    float oo[4][4];
#pragma unroll
    for (int i = 0; i < 4; ++i)
#pragma unroll
        for (int j = 0; j < 4; ++j) oo[i][j] = 0.f;

#pragma unroll 8
    for (int k2 = 0; k2 < 64; ++k2) {
        uint4 w = *(const uint4*)(wbp + k2 * 64 + ch * 4);
        int chunk = q ^ (k2 & 15);
        uint4 g = *(const uint4*)(gT2 + k2 * 64 + chunk * 4);
#define P2(i, gv) \
        oo[i][0]=dot2f(gv,w.x,oo[i][0]); oo[i][1]=dot2f(gv,w.y,oo[i][1]); \
        oo[i][2]=dot2f(gv,w.z,oo[i][2]); oo[i][3]=dot2f(gv,w.w,oo[i][3]);
        P2(0, g.x) P2(1, g.y) P2(2, g.z) P2(3, g.w)
#undef P2
    }

    // bias + SiLU + LN (reduce across the 16 in-wave channel owners)
    float4 bbv = *(const float4*)(bb + ch * 4);
    float bz[4] = {bbv.x, bbv.y, bbv.z, bbv.w};
    float s[4], qv[4];
#pragma unroll
    for (int i = 0; i < 4; ++i) {
        float ss = 0.f, qq = 0.f;
#pragma unroll
        for (int j = 0; j < 4; ++j) {
            float t = oo[i][j] + bz[j];
            t = t / (1.f + __expf(-t));
            oo[i][j] = t;
            ss += t;
            qq = fmaf(t, t, qq);
        }
        s[i] = ss; qv[i] = qq;
    }

#pragma unroll
    for (int d2 = 1; d2 < 16; d2 <<= 1) {
#pragma unroll
        for (int i = 0; i < 4; ++i) {
            s[i]  += __shfl_xor(s[i],  d2, 64);
            qv[i] += __shfl_xor(qv[i], d2, 64);
        }
    }

#pragma unroll
    for (int i = 0; i < 4; ++i) {
        float mu  = s[i] * (1.f / D);
        float var = qv[i] * (1.f / D) - mu * mu;
        float inv = rsqrtf(var + EPSL);
        int node = base + q * 4 + i;
        if (node < N) {
            uint2 pk;
            pk.x = packh2((oo[i][0] - mu) * inv, (oo[i][1] - mu) * inv);
            pk.y = packh2((oo[i][2] - mu) * inv, (oo[i][3] - mu) * inv);
            *(uint2*)(m + (size_t)node * D + ch * 4) = pk;   // 8B store
        }
    }
}

// =======================================================================
// Initial embedding (round-7 proven, unchanged; fp32 h output).
// =======================================================================
__global__ __launch_bounds__(256) void k_init(const float* __restrict__ x,
                                              const float* __restrict__ w0,  // [16][64]
                                              const float* __restrict__ b0,
                                              const float* __restrict__ w1,  // [64][64]
                                              const float* __restrict__ b1,
                                              float* __restrict__ h, int N)
{
    __shared__ __align__(16) float xT[D_IN * 64];
    __shared__ __align__(16) float gT[D * 64];

    const int tid  = threadIdx.x;
    const int ch   = tid & 15;
    const int q    = tid >> 4;
    const int base = blockIdx.x * 64;

    {
        int sn = tid & 63;
        int sc = tid >> 6;
        int gn = min(base + sn, N - 1);
        float4 xv = *(const float4*)(x + (size_t)gn * D_IN + sc * 4);
        float* w = xT + (sc * 4) * 64 + sn;
        w[0*64] = xv.x; w[1*64] = xv.y; w[2*64] = xv.z; w[3*64] = xv.w;
    }
    __syncthreads();

    float acc[4][4];
#pragma unroll
    for (int i = 0; i < 4; ++i)
#pragma unroll
        for (int c = 0; c < 4; ++c) acc[i][c] = 0.f;

#pragma unroll
    for (int k = 0; k < D_IN; ++k) {
        float4 w = *(const float4*)(w0 + k * D + ch * 4);
        float4 xv = *(const float4*)(xT + k * 64 + q * 4);
#define PP(i, xc) \
        acc[i][0]=fmaf(xc,w.x,acc[i][0]); acc[i][1]=fmaf(xc,w.y,acc[i][1]); \
        acc[i][2]=fmaf(xc,w.z,acc[i][2]); acc[i][3]=fmaf(xc,w.w,acc[i][3]);
        PP(0, xv.x) PP(1, xv.y) PP(2, xv.z) PP(3, xv.w)
#undef PP
    }

    {
        float4 b0v = *(const float4*)(b0 + ch * 4);
        float bav[4] = {b0v.x, b0v.y, b0v.z, b0v.w};
        int chunk = q ^ (ch >> 1);      // r = 4ch+c -> r>>3 = ch>>1
#pragma unroll
        for (int c = 0; c < 4; ++c) {
            int r = ch * 4 + c;
            float4 t;
            t.x = fmaxf(acc[0][c] + bav[c], 0.f);
            t.y = fmaxf(acc[1][c] + bav[c], 0.f);
            t.z = fmaxf(acc[2][c] + bav[c], 0.f);
            t.w = fmaxf(acc[3][c] + bav[c], 0.f);
            *(float4*)(gT + r * 64 + chunk * 4) = t;
        }
    }
    __syncthreads();

    float4 o0 = {0,0,0,0}, o1 = {0,0,0,0}, o2 = {0,0,0,0}, o3 = {0,0,0,0};
#pragma unroll 8
    for (int k = 0; k < D; ++k) {
        float4 w = *(const float4*)(w1 + k * D + ch * 4);
        int chunk = q ^ ((k >> 3) & 15);
        float4 g = *(const float4*)(gT + k * 64 + chunk * 4);
        o0.x=fmaf(g.x,w.x,o0.x); o0.y=fmaf(g.x,w.y,o0.y); o0.z=fmaf(g.x,w.z,o0.z); o0.w=fmaf(g.x,w.w,o0.w);
        o1.x=fmaf(g.y,w.x,o1.x); o1.y=fmaf(g.y,w.y,o1.y); o1.z=fmaf(g.y,w.z,o1.z); o1.w=fmaf(g.y,w.w,o1.w);
        o2.x=fmaf(g.z,w.x,o2.x); o2.y=fmaf(g.z,w.y,o2.y); o2.z=fmaf(g.z,w.z,o2.z); o2.w=fmaf(g.z,w.w,o2.w);
        o3.x=fmaf(g.w,w.x,o3.x); o3.y=fmaf(g.w,w.y,o3.y); o3.z=fmaf(g.w,w.z,o3.z); o3.w=fmaf(g.w,w.w,o3.w);
    }

    float4 bbv = *(const float4*)(b1 + ch * 4);
    float s[4], qv[4];
#define FIN(i, ov) { \
        ov.x += bbv.x; ov.y += bbv.y; ov.z += bbv.z; ov.w += bbv.w; \
        ov.x = ov.x / (1.f + __expf(-ov.x)); ov.y = ov.y / (1.f + __expf(-ov.y)); \
        ov.z = ov.z / (1.f + __expf(-ov.z)); ov.w = ov.w / (1.f + __expf(-ov.w)); \
        s[i]  = (ov.x + ov.y) + (ov.z + ov.w); \
        qv[i] = fmaf(ov.x, ov.x, fmaf(ov.y, ov.y, fmaf(ov.z, ov.z, ov.w * ov.w))); }
    FIN(0, o0) FIN(1, o1) FIN(2, o2) FIN(3, o3)
#undef FIN

#pragma unroll
    for (int d2 = 1; d2 < 16; d2 <<= 1) {
#pragma unroll
        for (int i = 0; i < 4; ++i) {
            s[i]  += __shfl_xor(s[i],  d2, 64);
            qv[i] += __shfl_xor(qv[i], d2, 64);
        }
    }

#pragma unroll
    for (int i = 0; i < 4; ++i) {
        float mu  = s[i] * (1.f / D);
        float var = qv[i] * (1.f / D) - mu * mu;
        float inv = rsqrtf(var + EPSL);
        int node = base + q * 4 + i;
        if (node < N) {
            float4 ov = (i == 0) ? o0 : (i == 1) ? o1 : (i == 2) ? o2 : o3;
            float4 outv;
            outv.x = (ov.x - mu) * inv;
            outv.y = (ov.y - mu) * inv;
            outv.z = (ov.z - mu) * inv;
            outv.w = (ov.w - mu) * inv;
            *(float4*)(h + (size_t)node * D + ch * 4) = outv;
        }
    }
}

// ---------------- aggregation: h += segment_mean(m[src], dst) ------------------
// m fp16 (8B per lane per edge); unroll 4 (round-9 proven)
__global__ __launch_bounds__(256) void k_agg(const __half* __restrict__ m,
                                             const int* __restrict__ csr,
                                             const int* __restrict__ off,
                                             float* __restrict__ h, int N)
{
    int g = threadIdx.x >> 4;
    int c = threadIdx.x & 15;
    int node = blockIdx.x * 16 + g;
    if (node >= N) return;

    int b  = off[node];
    int e2 = off[node + 1];
    float4 s0 = {0.f, 0.f, 0.f, 0.f};
    float4 s1 = {0.f, 0.f, 0.f, 0.f};
    int e = b;
#define GATH(sacc, pv) { \
        float2 u0 = __half22float2(*reinterpret_cast<__half2*>(&pv.x)); \
        float2 u1 = __half22float2(*reinterpret_cast<__half2*>(&pv.y)); \
        sacc.x += u0.x; sacc.y += u0.y; sacc.z += u1.x; sacc.w += u1.y; }
    for (; e + 4 <= e2; e += 4) {
        int sn0 = csr[e], sn1 = csr[e + 1], sn2 = csr[e + 2], sn3 = csr[e + 3];
        int2 p0 = ((const int2*)(m + (size_t)sn0 * D))[c];
        int2 p1 = ((const int2*)(m + (size_t)sn1 * D))[c];
        int2 p2 = ((const int2*)(m + (size_t)sn2 * D))[c];
        int2 p3 = ((const int2*)(m + (size_t)sn3 * D))[c];
        GATH(s0, p0) GATH(s1, p1) GATH(s0, p2) GATH(s1, p3)
    }
    for (; e < e2; ++e) {
        int sn = csr[e];
        int2 p = ((const int2*)(m + (size_t)sn * D))[c];
        GATH(s0, p)
    }
#undef GATH
    s0.x += s1.x; s0.y += s1.y; s0.z += s1.z; s0.w += s1.w;

    float dnm = fmaxf((float)(e2 - b), 1.f);
    float inv = 1.f / dnm;

    float4* hp = (float4*)(h + (size_t)node * D);
    float4 hv = hp[c];
    hv.x = fmaf(s0.x, inv, hv.x);
    hv.y = fmaf(s0.y, inv, hv.y);
    hv.z = fmaf(s0.z, inv, hv.z);
    hv.w = fmaf(s0.w, inv, hv.w);
    hp[c] = hv;
}

extern "C" void kernel_launch(void* const* d_in, const int* in_sizes, int n_in,
                              void* d_out, int out_size, void* d_ws, size_t ws_size,
                              hipStream_t stream)
{
    const float* x  = (const float*)d_in[0];
    const int*   ei = (const int*)d_in[1];
    const float* w0 = (const float*)d_in[2];
    const float* b0 = (const float*)d_in[3];
    const float* w1 = (const float*)d_in[4];
    const float* b1 = (const float*)d_in[5];
    const float* wa = (const float*)d_in[6];
    const float* ba = (const float*)d_in[7];
    const float* wb = (const float*)d_in[8];
    const float* bb = (const float*)d_in[9];

    const int N = in_sizes[0] / D_IN;
    const int E = in_sizes[1] / 2;
    const int L = in_sizes[6] / (D * H);

    const int* src = ei;
    const int* dst = ei + E;

    // workspace layout (256B aligned chunks)
    char* ws = (char*)d_ws;
    size_t o = 0;
    auto carve = [&](size_t bytes) -> char* {
        char* p = ws + o;
        o = (o + bytes + 255) & ~(size_t)255;
        return p;
    };
    __half* m          = (__half*)carve((size_t)N * D * sizeof(__half));
    int*   csr         = (int*)  carve((size_t)E * sizeof(int));
    int*   cnt         = (int*)  carve((size_t)N * sizeof(int));
    int*   fill        = (int*)  carve((size_t)N * sizeof(int));
    int*   offp        = (int*)  carve((size_t)(N + 1) * sizeof(int));
    int*   bsum        = (int*)  carve((size_t)1024 * sizeof(int));
    unsigned int* wap  = (unsigned int*)carve((size_t)L * 4096 * sizeof(unsigned int));
    unsigned int* wbp  = (unsigned int*)carve((size_t)L * 4096 * sizeof(unsigned int));

    float* h = (float*)d_out;

    const int nb = (N + 63) / 64;
    const int G1 = (N + 255) / 256;

    k_zero<<<(N + 255) / 256, 256, 0, stream>>>(cnt, N);
    k_zero<<<(N + 255) / 256, 256, 0, stream>>>(fill, N);
    k_hist<<<(E + 255) / 256, 256, 0, stream>>>(dst, cnt, E);
    k_scan_blk<<<G1, 256, 0, stream>>>(cnt, offp, bsum, N);
    k_scan_top<<<1, 1024, 0, stream>>>(bsum, G1);
    k_scan_add<<<G1, 256, 0, stream>>>(offp, bsum, N);
    k_fill_x<<<2048, 256, 0, stream>>>(src, dst, offp, fill, csr, E);
    k_prep_w<<<(L * 8192 + 255) / 256, 256, 0, stream>>>(wa, wb, wap, wbp, L);

    k_init<<<nb, 256, 0, stream>>>(x, w0, b0, w1, b1, h, N);

    for (int l = 0; l < L; ++l) {
        k_mlp<<<nb, 256, 0, stream>>>(h, wap + (size_t)l * 4096,
                                      ba + (size_t)l * H,
                                      wbp + (size_t)l * 4096,
                                      bb + (size_t)l * D, m, N);
        k_agg<<<(N + 15) / 16, 256, 0, stream>>>(m, csr, offp, h, N);
    }
}